// Round 2
// baseline (288.736 us; speedup 1.0000x reference)
//
#include <hip/hip_runtime.h>
#include <math.h>

#define T_TOK 2048
#define HD 768
#define ID 1536
#define NE 8
#define CAP 768
#define TK 4096

typedef __bf16 bf16_t;
typedef __bf16 bf16x8 __attribute__((ext_vector_type(8)));
typedef __bf16 bf16x4 __attribute__((ext_vector_type(4)));
typedef float floatx4 __attribute__((ext_vector_type(4)));

__device__ __forceinline__ void gld16(const bf16_t* g, bf16_t* l) {
  __builtin_amdgcn_global_load_lds(
      (__attribute__((address_space(1))) void*)(g),
      (__attribute__((address_space(3))) void*)(l),
      16, 0, 0);
}

// ---------------- K1: fused cast + routing (wave per token) ----------------
__global__ void k_route(const float* __restrict__ x, const float* __restrict__ wg,
                        bf16_t* __restrict__ xbf, int2* __restrict__ idx2,
                        float2* __restrict__ wc2, int2* __restrict__ tok_rows,
                        float* __restrict__ imp) {
  int t = blockIdx.x * 4 + (threadIdx.x >> 6);
  int lane = threadIdx.x & 63;
  const float* xr = x + (size_t)t * HD;
  int off = lane * 12;
  float4 a = *(const float4*)(xr + off);
  float4 b = *(const float4*)(xr + off + 4);
  float4 c = *(const float4*)(xr + off + 8);
  float xv[12] = {a.x, a.y, a.z, a.w, b.x, b.y, b.z, b.w, c.x, c.y, c.z, c.w};
  bf16x4 s0, s1, s2;
#pragma unroll
  for (int j = 0; j < 4; ++j) { s0[j] = (bf16_t)xv[j]; s1[j] = (bf16_t)xv[4 + j]; s2[j] = (bf16_t)xv[8 + j]; }
  bf16_t* xo = xbf + (size_t)t * HD + off;
  *(bf16x4*)xo = s0; *(bf16x4*)(xo + 4) = s1; *(bf16x4*)(xo + 8) = s2;

  float acc[8] = {0, 0, 0, 0, 0, 0, 0, 0};
#pragma unroll
  for (int jj = 0; jj < 12; ++jj) {
    const float4* wr = (const float4*)(wg + (size_t)(off + jj) * 8);
    float4 w0 = wr[0], w1 = wr[1];
    float v = xv[jj];
    acc[0] += v * w0.x; acc[1] += v * w0.y; acc[2] += v * w0.z; acc[3] += v * w0.w;
    acc[4] += v * w1.x; acc[5] += v * w1.y; acc[6] += v * w1.z; acc[7] += v * w1.w;
  }
#pragma unroll
  for (int e = 0; e < 8; ++e) {
    float v = acc[e];
    for (int s = 1; s < 64; s <<= 1) v += __shfl_xor(v, s, 64);
    acc[e] = v;
  }
  float mx = acc[0];
#pragma unroll
  for (int e = 1; e < 8; ++e) mx = fmaxf(mx, acc[e]);
  float p[8], sum = 0.f;
#pragma unroll
  for (int e = 0; e < 8; ++e) { p[e] = __expf(acc[e] - mx); sum += p[e]; }
#pragma unroll
  for (int e = 0; e < 8; ++e) p[e] /= sum;
  if (lane < 8) atomicAdd(&imp[lane], p[lane]);
  if (lane == 0) {
    int e0 = 0;
#pragma unroll
    for (int e = 1; e < 8; ++e) if (p[e] > p[e0]) e0 = e;
    int e1 = (e0 == 0) ? 1 : 0;
#pragma unroll
    for (int e = 0; e < 8; ++e) if (e != e0 && p[e] > p[e1]) e1 = e;
    float denom = p[e0] + p[e1] + 1e-8f;
    float w0c = fminf(fmaxf(p[e0] / denom, 1e-8f), 10.f);
    float w1c = fminf(fmaxf(p[e1] / denom, 1e-8f), 10.f);
    idx2[t] = make_int2(e0, e1);
    wc2[t] = make_float2(w0c, w1c);
    tok_rows[t] = make_int2(-1, -1);
  }
}

// ---------------- K2: capacity ranks + placement (16 waves) ----------------
__global__ void k_scan(const int2* __restrict__ idx2, const float2* __restrict__ wc2,
                       const float* __restrict__ imp,
                       int* __restrict__ tok_of_row, float* __restrict__ wgt_of_row,
                       int2* __restrict__ tok_rows, int2* __restrict__ cnt_start,
                       float* __restrict__ aux_out) {
  __shared__ int sTot[16];
  __shared__ int sPos[8];
  int tid = threadIdx.x;
  int w = tid >> 6, lane = tid & 63;
  int s = w >> 3, e = w & 7;
  int t0 = lane * 32;
  int cnt = 0;
  for (int j = 0; j < 32; ++j) {
    int2 p = idx2[t0 + j];
    int ex = s ? p.y : p.x;
    cnt += (ex == e) ? 1 : 0;
  }
  int incl = cnt;
  for (int d = 1; d < 64; d <<= 1) {
    int v = __shfl_up(incl, d, 64);
    if (lane >= d) incl += v;
  }
  int excl = incl - cnt;
  if (lane == 63) sTot[w] = incl;
  __syncthreads();
  if (tid == 0) {
    int run = 0;
    float a = 0.f;
    for (int ee = 0; ee < 8; ++ee) {
      int k = min(sTot[ee], CAP) + min(sTot[8 + ee], CAP);
      sPos[ee] = run;
      cnt_start[ee] = make_int2(run, k);
      a += ((float)k / (float)TK) * (imp[ee] / (float)T_TOK);
      run += k;
    }
    a *= (float)NE;
    int dropped = TK - run;
    if (dropped > 0) a += (float)dropped / (float)T_TOK * 0.1f;
    a = fminf(a, 1.f) * 0.001f;
    aux_out[0] = a;
  }
  __syncthreads();
  int rank = excl;
  for (int j = 0; j < 32; ++j) {
    int t = t0 + j;
    int2 p = idx2[t];
    int ex = s ? p.y : p.x;
    if (ex == e) {
      rank++;
      if (rank <= CAP) {
        int pos = atomicAdd(&sPos[e], 1);
        tok_of_row[pos] = t;
        float2 wv = wc2[t];
        wgt_of_row[pos] = s ? wv.y : wv.x;
        ((int*)tok_rows)[2 * t + s] = pos;
      }
    }
  }
}

// ---------------- K3: merged weight transpose fp32->bf16 ----------------
__global__ void k_tr(const float* __restrict__ w1, const float* __restrict__ w3,
                     const float* __restrict__ w2, bf16_t* __restrict__ w1t,
                     bf16_t* __restrict__ w3t, bf16_t* __restrict__ w2t) {
  __shared__ bf16_t tl[64][65];
  int z = blockIdx.z;
  const float* src; bf16_t* dst; int R, C, r0, c0;
  if (z < 16) {
    R = HD; C = ID; r0 = blockIdx.y * 64; c0 = blockIdx.x * 64;
    int e = z & 7;
    if (z < 8) { src = w1 + (size_t)e * R * C; dst = w1t + (size_t)e * R * C; }
    else       { src = w3 + (size_t)e * R * C; dst = w3t + (size_t)e * R * C; }
  } else {
    R = ID; C = HD; r0 = blockIdx.x * 64; c0 = blockIdx.y * 64;
    int e = z - 16;
    src = w2 + (size_t)e * R * C; dst = w2t + (size_t)e * R * C;
  }
  int tid = threadIdx.x;
  int lr = tid >> 2, lc = (tid & 3) * 16;
  const float* sp = src + (size_t)(r0 + lr) * C + c0 + lc;
#pragma unroll
  for (int j = 0; j < 16; j += 4) {
    float4 v = *(const float4*)(sp + j);
    tl[lr][lc + j + 0] = (bf16_t)v.x;
    tl[lr][lc + j + 1] = (bf16_t)v.y;
    tl[lr][lc + j + 2] = (bf16_t)v.z;
    tl[lr][lc + j + 3] = (bf16_t)v.w;
  }
  __syncthreads();
  int oc = tid >> 2, orr = (tid & 3) * 16;
  bf16_t* d = dst + (size_t)(c0 + oc) * R + r0 + orr;
  bf16x8 v0, v1;
#pragma unroll
  for (int j = 0; j < 8; ++j) v0[j] = tl[orr + j][oc];
#pragma unroll
  for (int j = 0; j < 8; ++j) v1[j] = tl[orr + 8 + j][oc];
  *(bf16x8*)d = v0;
  *(bf16x8*)(d + 8) = v1;
}

// ---------------- K4: grouped GEMM1 (g,u) + SiLU -> h ----------------
// grid (96, 24): e = bx&7 (XCD-pinned), j = bx>>3, tile 128m x 64n
__global__ __launch_bounds__(256, 3)
void k_gemm1(const bf16_t* __restrict__ xbf, const bf16_t* __restrict__ w1t,
             const bf16_t* __restrict__ w3t, const int* __restrict__ tok_of_row,
             const int2* __restrict__ cnt_start, bf16_t* __restrict__ h_ws) {
  int e = blockIdx.x & 7, j = blockIdx.x >> 3;
  int2 cs = cnt_start[e];
  int nrows = cs.y - j * 128;
  if (nrows <= 0) return;
  if (nrows > 128) nrows = 128;
  int grow0 = cs.x + j * 128;
  int cy = blockIdx.y;

  __shared__ __attribute__((aligned(16))) bf16_t Abuf[128 * 32];
  __shared__ __attribute__((aligned(16))) bf16_t B1buf[64 * 32];
  __shared__ __attribute__((aligned(16))) bf16_t B3buf[64 * 32];

  int tid = threadIdx.x;
  int lane = tid & 63, wv = tid >> 6;
  int wm = wv & 1, wn = wv >> 1;
  int lr = lane & 15, q = lane >> 4;
  int rdc = (q ^ ((lane >> 1) & 3)) * 8;
  int srow = lane >> 2;
  int gch = ((lane & 3) ^ ((lane >> 3) & 3)) * 8;

  int ra = wv * 32 + srow;
  int tokA0 = tok_of_row[grow0 + min(ra, nrows - 1)];
  int tokA1 = tok_of_row[grow0 + min(ra + 16, nrows - 1)];
  const bf16_t* gA0 = xbf + (size_t)tokA0 * HD + gch;
  const bf16_t* gA1 = xbf + (size_t)tokA1 * HD + gch;
  int nb = cy * 64 + wv * 16 + srow;
  const bf16_t* gB1 = w1t + ((size_t)e * ID + nb) * HD + gch;
  const bf16_t* gB3 = w3t + ((size_t)e * ID + nb) * HD + gch;
  bf16_t* lA0 = &Abuf[(wv * 32) * 32];
  bf16_t* lA1 = &Abuf[(wv * 32 + 16) * 32];
  bf16_t* lB1 = &B1buf[(wv * 16) * 32];
  bf16_t* lB3 = &B3buf[(wv * 16) * 32];

  floatx4 accg[4][2] = {};
  floatx4 accu[4][2] = {};

  for (int kk = 0; kk < 24; ++kk) {
    __syncthreads();
    gld16(gA0, lA0); gld16(gA1, lA1);
    gld16(gB1, lB1); gld16(gB3, lB3);
    gA0 += 32; gA1 += 32; gB1 += 32; gB3 += 32;
    __syncthreads();
    bf16x8 af[4], b1f[2], b3f[2];
#pragma unroll
    for (int i = 0; i < 4; ++i) af[i] = *(const bf16x8*)&Abuf[(wm * 64 + i * 16 + lr) * 32 + rdc];
#pragma unroll
    for (int i = 0; i < 2; ++i) b1f[i] = *(const bf16x8*)&B1buf[(wn * 32 + i * 16 + lr) * 32 + rdc];
#pragma unroll
    for (int i = 0; i < 2; ++i) b3f[i] = *(const bf16x8*)&B3buf[(wn * 32 + i * 16 + lr) * 32 + rdc];
#pragma unroll
    for (int i = 0; i < 4; ++i)
#pragma unroll
      for (int jj = 0; jj < 2; ++jj) {
        accg[i][jj] = __builtin_amdgcn_mfma_f32_16x16x32_bf16(af[i], b1f[jj], accg[i][jj], 0, 0, 0);
        accu[i][jj] = __builtin_amdgcn_mfma_f32_16x16x32_bf16(af[i], b3f[jj], accu[i][jj], 0, 0, 0);
      }
  }
#pragma unroll
  for (int i = 0; i < 4; ++i)
#pragma unroll
    for (int r = 0; r < 4; ++r) {
      int rl = wm * 64 + i * 16 + q * 4 + r;
      if (rl < nrows) {
        size_t rb = (size_t)(grow0 + rl) * ID + cy * 64 + wn * 32 + lr;
#pragma unroll
        for (int jj = 0; jj < 2; ++jj) {
          float gg = accg[i][jj][r], uu = accu[i][jj][r];
          float sg = gg / (1.f + __expf(-gg));
          h_ws[rb + jj * 16] = (bf16_t)(sg * uu);
        }
      }
    }
}

// ---------------- K5: grouped GEMM2 + fused combine (atomicAdd) ----------------
// grid (96, 12): e = bx&7 (XCD-pinned), j = bx>>3, tile 128m x 64n
__global__ __launch_bounds__(256, 4)
void k_gemm2(const bf16_t* __restrict__ h_ws, const bf16_t* __restrict__ w2t,
             const int* __restrict__ tok_of_row, const float* __restrict__ wgt_of_row,
             const int2* __restrict__ cnt_start, float* __restrict__ out) {
  int e = blockIdx.x & 7, j = blockIdx.x >> 3;
  int2 cs = cnt_start[e];
  int nrows = cs.y - j * 128;
  if (nrows <= 0) return;
  if (nrows > 128) nrows = 128;
  int grow0 = cs.x + j * 128;
  int cy = blockIdx.y;

  __shared__ __attribute__((aligned(16))) bf16_t Abuf[128 * 32];
  __shared__ __attribute__((aligned(16))) bf16_t Bbuf[64 * 32];

  int tid = threadIdx.x;
  int lane = tid & 63, wv = tid >> 6;
  int wm = wv & 1, wn = wv >> 1;
  int lr = lane & 15, q = lane >> 4;
  int rdc = (q ^ ((lane >> 1) & 3)) * 8;
  int srow = lane >> 2;
  int gch = ((lane & 3) ^ ((lane >> 3) & 3)) * 8;

  int ra = wv * 32 + srow;
  const bf16_t* gA0 = h_ws + (size_t)(grow0 + min(ra, nrows - 1)) * ID + gch;
  const bf16_t* gA1 = h_ws + (size_t)(grow0 + min(ra + 16, nrows - 1)) * ID + gch;
  int nb = cy * 64 + wv * 16 + srow;
  const bf16_t* gB = w2t + ((size_t)e * HD + nb) * ID + gch;
  bf16_t* lA0 = &Abuf[(wv * 32) * 32];
  bf16_t* lA1 = &Abuf[(wv * 32 + 16) * 32];
  bf16_t* lB = &Bbuf[(wv * 16) * 32];

  floatx4 acc[4][2] = {};

  for (int kk = 0; kk < 48; ++kk) {
    __syncthreads();
    gld16(gA0, lA0); gld16(gA1, lA1);
    gld16(gB, lB);
    gA0 += 32; gA1 += 32; gB += 32;
    __syncthreads();
    bf16x8 af[4], bfr[2];
#pragma unroll
    for (int i = 0; i < 4; ++i) af[i] = *(const bf16x8*)&Abuf[(wm * 64 + i * 16 + lr) * 32 + rdc];
#pragma unroll
    for (int i = 0; i < 2; ++i) bfr[i] = *(const bf16x8*)&Bbuf[(wn * 32 + i * 16 + lr) * 32 + rdc];
#pragma unroll
    for (int i = 0; i < 4; ++i)
#pragma unroll
      for (int jj = 0; jj < 2; ++jj)
        acc[i][jj] = __builtin_amdgcn_mfma_f32_16x16x32_bf16(af[i], bfr[jj], acc[i][jj], 0, 0, 0);
  }
#pragma unroll
  for (int i = 0; i < 4; ++i)
#pragma unroll
    for (int r = 0; r < 4; ++r) {
      int rl = wm * 64 + i * 16 + q * 4 + r;
      if (rl < nrows) {
        int grow = grow0 + rl;
        int tok = tok_of_row[grow];
        float wgt = wgt_of_row[grow];
        size_t ob = (size_t)tok * HD + cy * 64 + wn * 32 + lr;
#pragma unroll
        for (int jj = 0; jj < 2; ++jj)
          atomicAdd(&out[ob + jj * 16], wgt * acc[i][jj][r]);
      }
    }
}

extern "C" void kernel_launch(void* const* d_in, const int* in_sizes, int n_in,
                              void* d_out, int out_size, void* d_ws, size_t ws_size,
                              hipStream_t stream) {
  const float* x  = (const float*)d_in[0];
  const float* wg = (const float*)d_in[1];
  const float* w1 = (const float*)d_in[2];
  const float* w3 = (const float*)d_in[3];
  const float* w2 = (const float*)d_in[4];
  float* out = (float*)d_out;

  char* ws = (char*)d_ws;
  bf16_t* xbf  = (bf16_t*)(ws + 0);          //  3,145,728
  bf16_t* w1t  = (bf16_t*)(ws + 3145728);    // 18,874,368
  bf16_t* w3t  = (bf16_t*)(ws + 22020096);   // 18,874,368
  bf16_t* w2t  = (bf16_t*)(ws + 40894464);   // 18,874,368
  bf16_t* h_ws = (bf16_t*)(ws + 59768832);   // 12,582,912
  int2*   idx2 = (int2*)(ws + 72351744);
  float2* wc2  = (float2*)(ws + 72368128);
  int*    tok_of_row = (int*)(ws + 72384512);
  float*  wgt_of_row = (float*)(ws + 72400896);
  int2*   tok_rows   = (int2*)(ws + 72417280);
  int2*   cnt_start  = (int2*)(ws + 72433664);
  float*  imp        = (float*)(ws + 72433728);

  float* aux_out = out + (size_t)T_TOK * HD;

  hipMemsetAsync(out, 0, (size_t)T_TOK * HD * sizeof(float), stream);
  hipMemsetAsync(imp, 0, NE * sizeof(float), stream);
  k_route<<<512, 256, 0, stream>>>(x, wg, xbf, idx2, wc2, tok_rows, imp);
  k_scan<<<1, 1024, 0, stream>>>(idx2, wc2, imp, tok_of_row, wgt_of_row,
                                 tok_rows, cnt_start, aux_out);
  k_tr<<<dim3(24, 12, 24), 256, 0, stream>>>(w1, w3, w2, w1t, w3t, w2t);
  k_gemm1<<<dim3(96, 24), 256, 0, stream>>>(xbf, w1t, w3t, tok_of_row,
                                            cnt_start, h_ws);
  k_gemm2<<<dim3(96, 12), 256, 0, stream>>>(h_ws, w2t, tok_of_row, wgt_of_row,
                                            cnt_start, out);
}